// Round 5
// baseline (339.437 us; speedup 1.0000x reference)
//
#include <hip/hip_runtime.h>
#include <hip/hip_bf16.h>

#define K_DIM 8192
#define L_DIM 1024
#define C2 240
#define MSTRIDE 256                 // padded m stride in partials
#define BM 128
#define BN 64
#define BK 64
#define KSPLIT 16
#define KCHUNK 512                  // K_DIM / KSPLIT
#define NSTEP 8                     // KCHUNK / BK
#define PART_KC (L_DIM * MSTRIDE)   // 262144 bf16 elems per k-chunk
#define NBLK 512
#define NTILES 16                   // L_DIM / BN
#define CONTRIB 32                  // KSPLIT * 2 m-tiles per n-tile
#define HELPERS 4                   // last 4 arrivals compute colbuf
#define DONE_TARGET (NTILES * HELPERS)
#define TOT_F4 (10000 * 256)
#define SPIN_MAX (1 << 22)

typedef __attribute__((ext_vector_type(4))) float f32x4;
typedef __attribute__((ext_vector_type(8))) short bf16x8;
typedef __attribute__((ext_vector_type(4))) short bf16x4;

__device__ __forceinline__ unsigned short f2bf(float f) {
  return __builtin_bit_cast(unsigned short, __float2bfloat16(f));
}
__device__ __forceinline__ float bf2f(unsigned short h) {
  unsigned u = ((unsigned)h) << 16;
  return __builtin_bit_cast(float, u);
}
__device__ __forceinline__ int aload(int* p) {
  return __hip_atomic_load(p, __ATOMIC_ACQUIRE, __HIP_MEMORY_SCOPE_AGENT);
}

// Single kernel, 512 blocks x 256 threads, __launch_bounds__(256,2) ->
// 2 blocks/CU co-resident (LDS 48KB, VGPR<=256). Phases chained by
// device-scope atomic counters + fences (no cooperative launch):
//  A: bf16 MFMA k-split GEMM tile -> part[kc][n][m] (bf16, in d_out)
//  B: per n-tile, last-4 arrivals compute colbuf[64 cols] (16 each)
//  C: all blocks spin on done==64, then broadcast colbuf/1024.
// Deadlock-safe: B-spin waits on a monotone counter fed by work already
// done; C-spin requires co-residency, guaranteed by capacity arithmetic.
__global__ __launch_bounds__(256, 2) void k_fused(
    const float* __restrict__ Wm, const float* __restrict__ Am,
    const float* __restrict__ b3, const float* __restrict__ w4,
    const float* __restrict__ b4, unsigned short* __restrict__ part,
    float* __restrict__ colbuf, int* __restrict__ ctrs,
    float4* __restrict__ out)
{
  __shared__ __align__(16) unsigned short sW[2 * BM * BK];  // 32 KB dbuf
  __shared__ __align__(16) unsigned short sA[2 * BN * BK];  // 16 KB dbuf
  __shared__ float red[2][4];
  __shared__ int s_old;

  const int t    = threadIdx.x;
  const int lane = t & 63;
  const int bid  = blockIdx.x;

  // XCD-chunked remap: each XCD owns 2 consecutive k-chunks (all tiles).
  const int wk    = (bid & 7) * 64 + (bid >> 3);   // bijective (512%8==0)
  const int nt16  = wk & 15;
  const int mtile = (wk >> 4) & 1;
  const int kc    = wk >> 5;

  // ======================= Phase A: GEMM =======================
  {
    const int wid = t >> 6;
    const int mg  = wid & 1;        // 64-row group
    const int ng  = wid >> 1;       // 32-col group
    const int l15 = lane & 15;
    const int lk8 = (lane >> 4) * 8;

    const int n0b = nt16 * BN;
    const int m0b = mtile * BM;
    const int k0  = kc * KCHUNK;

    // staging: W thread -> (row t>>1, k-half (t&1)*32); A -> (n-quad, k-quad)
    const int swm = t >> 1;
    const int swk = (t & 1) * 32;
    const int san = (t & 15) * 4;
    const int sak = (t >> 4) * 4;

    const float* wp = Wm + (size_t)(m0b + swm) * K_DIM + k0 + swk;
    const float* ap = Am + (size_t)(k0 + sak) * L_DIM + n0b + san;
    const bool wok = (m0b + swm) < C2;

    f32x4 wreg[8], areg[4];
    f32x4 acc[4][2];
#pragma unroll
    for (int i = 0; i < 4; ++i)
#pragma unroll
      for (int j = 0; j < 2; ++j) acc[i][j] = (f32x4){0.f, 0.f, 0.f, 0.f};

    // prefetch step 0
#pragma unroll
    for (int j = 0; j < 8; ++j)
      wreg[j] = wok ? *(const f32x4*)(wp + 4 * j) : (f32x4){0.f, 0.f, 0.f, 0.f};
#pragma unroll
    for (int r = 0; r < 4; ++r)
      areg[r] = *(const f32x4*)(ap + (size_t)r * L_DIM);

    for (int s = 0; s < NSTEP; ++s) {
      unsigned short* swb = sW + (s & 1) * (BM * BK);
      unsigned short* sab = sA + (s & 1) * (BN * BK);

      // convert + swizzled LDS write into buffer s&1
#pragma unroll
      for (int j = 0; j < 4; ++j) {
        f32x4 a = wreg[2 * j], b = wreg[2 * j + 1];
        bf16x8 v;
        v[0] = (short)f2bf(a[0]); v[1] = (short)f2bf(a[1]);
        v[2] = (short)f2bf(a[2]); v[3] = (short)f2bf(a[3]);
        v[4] = (short)f2bf(b[0]); v[5] = (short)f2bf(b[1]);
        v[6] = (short)f2bf(b[2]); v[7] = (short)f2bf(b[3]);
        *(bf16x8*)&swb[swm * BK + ((swk + 8 * j) ^ ((swm & 7) << 3))] = v;
      }
#pragma unroll
      for (int j = 0; j < 4; ++j) {
        int n = san + j;
        bf16x4 v;
        v[0] = (short)f2bf(areg[0][j]); v[1] = (short)f2bf(areg[1][j]);
        v[2] = (short)f2bf(areg[2][j]); v[3] = (short)f2bf(areg[3][j]);
        *(bf16x4*)&sab[n * BK + (sak ^ ((n & 7) << 3))] = v;
      }
      __syncthreads();

      // issue next step's global loads (overlap with MFMA below)
      if (s + 1 < NSTEP) {
        const float* wp2 = wp + (s + 1) * BK;
        const float* ap2 = ap + (size_t)(s + 1) * BK * L_DIM;
#pragma unroll
        for (int j = 0; j < 8; ++j)
          wreg[j] = wok ? *(const f32x4*)(wp2 + 4 * j) : (f32x4){0.f, 0.f, 0.f, 0.f};
#pragma unroll
        for (int r = 0; r < 4; ++r)
          areg[r] = *(const f32x4*)(ap2 + (size_t)r * L_DIM);
      }

      // compute from LDS buffer s&1
#pragma unroll
      for (int kk = 0; kk < BK; kk += 32) {
        bf16x8 wf[4], af[2];
#pragma unroll
        for (int mt = 0; mt < 4; ++mt) {
          int m = mg * 64 + mt * 16 + l15;
          wf[mt] = *(const bf16x8*)&swb[m * BK + ((kk + lk8) ^ ((m & 7) << 3))];
        }
#pragma unroll
        for (int nt = 0; nt < 2; ++nt) {
          int n = ng * 32 + nt * 16 + l15;
          af[nt] = *(const bf16x8*)&sab[n * BK + ((kk + lk8) ^ ((n & 7) << 3))];
        }
#pragma unroll
        for (int mt = 0; mt < 4; ++mt)
#pragma unroll
          for (int nt = 0; nt < 2; ++nt)
            acc[mt][nt] = __builtin_amdgcn_mfma_f32_16x16x32_bf16(
                wf[mt], af[nt], acc[mt][nt], 0, 0, 0);
      }
      // no second barrier needed: next write targets the other buffer
    }

    // store transposed bf16 partials: part[kc][n][m], 8B per lane
    unsigned short* pb = part + (size_t)kc * PART_KC;
#pragma unroll
    for (int mt = 0; mt < 4; ++mt) {
      const int m0 = m0b + mg * 64 + mt * 16 + (lane >> 4) * 4;
#pragma unroll
      for (int nt = 0; nt < 2; ++nt) {
        const int n = n0b + ng * 32 + nt * 16 + l15;
        bf16x4 v;
        v[0] = (short)f2bf(acc[mt][nt][0]);
        v[1] = (short)f2bf(acc[mt][nt][1]);
        v[2] = (short)f2bf(acc[mt][nt][2]);
        v[3] = (short)f2bf(acc[mt][nt][3]);
        *(bf16x4*)&pb[(size_t)n * MSTRIDE + m0] = v;
      }
    }
  }

  // =============== Phase A->B handoff: publish partials ===============
  __threadfence();            // release this block's partial writes
  __syncthreads();
  if (t == 0)
    s_old = __hip_atomic_fetch_add(&ctrs[nt16], 1, __ATOMIC_ACQ_REL,
                                   __HIP_MEMORY_SCOPE_AGENT);
  __syncthreads();
  const int old = s_old;

  // ======================= Phase B: colbuf (helpers) =======================
  if (old >= CONTRIB - HELPERS) {
    if (t == 0) {
      int it = 0;
      while (aload(&ctrs[nt16]) < CONTRIB && it < SPIN_MAX) ++it;
    }
    __syncthreads();
    __threadfence();          // acquire all contributors' partials

    const int hslot = old - (CONTRIB - HELPERS);
    const float bias = (t < C2) ? b3[t] : 0.f;
    const float w4v  = (t < C2) ? w4[t] : 0.f;
    const int wv = t >> 6;
#pragma unroll 1
    for (int c = 0; c < BN / HELPERS; ++c) {
      const int n = nt16 * BN + hslot * (BN / HELPERS) + c;
      const unsigned short* p = part + (size_t)n * MSTRIDE + t;
      float ssum = 0.f;
#pragma unroll
      for (int kc2 = 0; kc2 < KSPLIT; ++kc2)
        ssum += bf2f(p[(size_t)kc2 * PART_KC]);
      float e  = fmaxf(ssum + bias, 0.f);   // rows >= 240: 0 + 0 -> 0
      float c4 = w4v * e;
#pragma unroll
      for (int off = 32; off; off >>= 1) {
        e  += __shfl_xor(e, off);
        c4 += __shfl_xor(c4, off);
      }
      if ((t & 63) == 0) { red[0][wv] = e; red[1][wv] = c4; }
      __syncthreads();
      if (t == 0) {
        const float cs  = red[0][0] + red[0][1] + red[0][2] + red[0][3];
        const float tc4 = red[1][0] + red[1][1] + red[1][2] + red[1][3] + b4[0];
        const float mask = 1.f / (1.f + expf(-tc4));
        colbuf[n] = cs * (1.f + mask) * (1.f / (float)L_DIM);
      }
      __syncthreads();
    }
    __threadfence();          // release colbuf writes
    __syncthreads();
    if (t == 0)
      __hip_atomic_fetch_add(&ctrs[NTILES], 1, __ATOMIC_ACQ_REL,
                             __HIP_MEMORY_SCOPE_AGENT);
  }

  // ======================= Phase C: broadcast =======================
  if (t == 0) {
    int it = 0;
    while (aload(&ctrs[NTILES]) < DONE_TARGET && it < SPIN_MAX) ++it;
  }
  __syncthreads();
  __threadfence();            // acquire colbuf
  const float4 v = ((const float4*)colbuf)[t];
  for (size_t i = (size_t)bid * 256 + t; i < TOT_F4; i += (size_t)NBLK * 256)
    out[i] = v;
}

extern "C" void kernel_launch(void* const* d_in, const int* in_sizes, int n_in,
                              void* d_out, int out_size, void* d_ws, size_t ws_size,
                              hipStream_t stream) {
  // inputs: x, edge_index, edge_attr, conv3_w, conv3_b, conv4_w, conv4_b
  const float* edge_attr = (const float*)d_in[2];   // [8192][1024]
  const float* w3        = (const float*)d_in[3];   // [240][8192]
  const float* b3        = (const float*)d_in[4];   // [240]
  const float* w4        = (const float*)d_in[5];   // [240]
  const float* b4        = (const float*)d_in[6];   // [1]

  unsigned short* part = (unsigned short*)d_out;    // [16][1024][256] bf16 = 8.4 MB
  float* colbuf = (float*)d_ws;                     // [1024] f32
  int* ctrs = (int*)((char*)d_ws + 4096);           // [16] ntile + [1] done
  float4* out4 = (float4*)d_out;

  hipMemsetAsync(ctrs, 0, 128, stream);
  k_fused<<<dim3(NBLK), 256, 0, stream>>>(w3, edge_attr, b3, w4, b4,
                                          part, colbuf, ctrs, out4);
}

// Round 6
// 49.036 us; speedup vs baseline: 6.9222x; 6.9222x over previous
//
#include <hip/hip_runtime.h>
#include <hip/hip_bf16.h>

#define K_DIM 8192
#define L_DIM 1024
#define C2 240
#define MSTRIDE 256                 // padded m stride in partials
#define BM 128
#define BN 64
#define BK 64
#define KSPLIT 16
#define KCHUNK 512                  // K_DIM / KSPLIT
#define NSTEP 8                     // KCHUNK / BK
#define PART_KC (L_DIM * MSTRIDE)   // 262144 bf16 elems per k-chunk
#define PART_BYTES ((size_t)KSPLIT * PART_KC * 2)  // 8,388,608
#define TOT_F4 (10000 * 256)

typedef __attribute__((ext_vector_type(4))) float f32x4;
typedef __attribute__((ext_vector_type(8))) short bf16x8;
typedef __attribute__((ext_vector_type(4))) short bf16x4;

__device__ __forceinline__ unsigned short f2bf(float f) {
  return __builtin_bit_cast(unsigned short, __float2bfloat16(f));
}
__device__ __forceinline__ float bf2f(unsigned short h) {
  unsigned u = ((unsigned)h) << 16;
  return __builtin_bit_cast(float, u);
}

// ---------------- Stage 1: bf16 MFMA K-split GEMM --------------------------
// part[kc][n][m(pad 256)] = (W[240][8192] @ A[8192][1024]) k-chunk partials.
// 512 blocks x 256 thr (4 waves, 2m x 2n of 64x32). XCD-chunked remap: each
// XCD owns 2 consecutive k-chunks (4MB A-slice + 1MB W-slice -> L2-local).
__global__ __launch_bounds__(256, 2) void k_gemm(
    const float* __restrict__ Wm, const float* __restrict__ Am,
    unsigned short* __restrict__ part)
{
  __shared__ __align__(16) unsigned short sW[2 * BM * BK];  // 32 KB dbuf
  __shared__ __align__(16) unsigned short sA[2 * BN * BK];  // 16 KB dbuf

  const int t    = threadIdx.x;
  const int lane = t & 63;
  const int bid  = blockIdx.x;

  const int wk    = (bid & 7) * 64 + (bid >> 3);   // bijective (512%8==0)
  const int nt16  = wk & 15;
  const int mtile = (wk >> 4) & 1;
  const int kc    = wk >> 5;

  const int wid = t >> 6;
  const int mg  = wid & 1;        // 64-row group
  const int ng  = wid >> 1;       // 32-col group
  const int l15 = lane & 15;
  const int lk8 = (lane >> 4) * 8;

  const int n0b = nt16 * BN;
  const int m0b = mtile * BM;
  const int k0  = kc * KCHUNK;

  // staging: W thread -> (row t>>1, k-half (t&1)*32)
  // A: sak spans {0,4,8,12} WITHIN each quarter-wave so the XOR swizzle
  // spreads writes across 8 slots (was 8-way bank conflict, now ~2-way).
  const int swm = t >> 1;
  const int swk = (t & 1) * 32;
  const int san = ((t >> 2) & 15) * 4;
  const int sak = (t & 3) * 4 + (t >> 6) * 16;

  const float* wp = Wm + (size_t)(m0b + swm) * K_DIM + k0 + swk;
  const float* ap = Am + (size_t)(k0 + sak) * L_DIM + n0b + san;
  const bool wok = (m0b + swm) < C2;

  f32x4 wreg[8], areg[4];
  f32x4 acc[4][2];
#pragma unroll
  for (int i = 0; i < 4; ++i)
#pragma unroll
    for (int j = 0; j < 2; ++j) acc[i][j] = (f32x4){0.f, 0.f, 0.f, 0.f};

  // prefetch step 0
#pragma unroll
  for (int j = 0; j < 8; ++j)
    wreg[j] = wok ? *(const f32x4*)(wp + 4 * j) : (f32x4){0.f, 0.f, 0.f, 0.f};
#pragma unroll
  for (int r = 0; r < 4; ++r)
    areg[r] = *(const f32x4*)(ap + (size_t)r * L_DIM);

  for (int s = 0; s < NSTEP; ++s) {
    unsigned short* swb = sW + (s & 1) * (BM * BK);
    unsigned short* sab = sA + (s & 1) * (BN * BK);

    // convert + swizzled LDS write into buffer s&1
#pragma unroll
    for (int j = 0; j < 4; ++j) {
      f32x4 a = wreg[2 * j], b = wreg[2 * j + 1];
      bf16x8 v;
      v[0] = (short)f2bf(a[0]); v[1] = (short)f2bf(a[1]);
      v[2] = (short)f2bf(a[2]); v[3] = (short)f2bf(a[3]);
      v[4] = (short)f2bf(b[0]); v[5] = (short)f2bf(b[1]);
      v[6] = (short)f2bf(b[2]); v[7] = (short)f2bf(b[3]);
      *(bf16x8*)&swb[swm * BK + ((swk + 8 * j) ^ ((swm & 7) << 3))] = v;
    }
#pragma unroll
    for (int j = 0; j < 4; ++j) {
      int n = san + j;
      bf16x4 v;
      v[0] = (short)f2bf(areg[0][j]); v[1] = (short)f2bf(areg[1][j]);
      v[2] = (short)f2bf(areg[2][j]); v[3] = (short)f2bf(areg[3][j]);
      *(bf16x4*)&sab[n * BK + (sak ^ ((n & 7) << 3))] = v;
    }
    __syncthreads();

    // issue next step's global loads (overlap with MFMA below)
    if (s + 1 < NSTEP) {
      const float* wp2 = wp + (s + 1) * BK;
      const float* ap2 = ap + (size_t)(s + 1) * BK * L_DIM;
#pragma unroll
      for (int j = 0; j < 8; ++j)
        wreg[j] = wok ? *(const f32x4*)(wp2 + 4 * j) : (f32x4){0.f, 0.f, 0.f, 0.f};
#pragma unroll
      for (int r = 0; r < 4; ++r)
        areg[r] = *(const f32x4*)(ap2 + (size_t)r * L_DIM);
    }

    // compute from LDS buffer s&1
#pragma unroll
    for (int kk = 0; kk < BK; kk += 32) {
      bf16x8 wf[4], af[2];
#pragma unroll
      for (int mt = 0; mt < 4; ++mt) {
        int m = mg * 64 + mt * 16 + l15;
        wf[mt] = *(const bf16x8*)&swb[m * BK + ((kk + lk8) ^ ((m & 7) << 3))];
      }
#pragma unroll
      for (int nt = 0; nt < 2; ++nt) {
        int n = ng * 32 + nt * 16 + l15;
        af[nt] = *(const bf16x8*)&sab[n * BK + ((kk + lk8) ^ ((n & 7) << 3))];
      }
#pragma unroll
      for (int mt = 0; mt < 4; ++mt)
#pragma unroll
        for (int nt = 0; nt < 2; ++nt)
          acc[mt][nt] = __builtin_amdgcn_mfma_f32_16x16x32_bf16(
              wf[mt], af[nt], acc[mt][nt], 0, 0, 0);
    }
    // single barrier per step is safe: next write targets the other buffer
  }

  // store transposed bf16 partials: part[kc][n][m], 8B per lane
  // (m >= 240 rows are zeros via wok zero-fill -> safe to read downstream)
  unsigned short* pb = part + (size_t)kc * PART_KC;
#pragma unroll
  for (int mt = 0; mt < 4; ++mt) {
    const int m0 = m0b + mg * 64 + mt * 16 + (lane >> 4) * 4;
#pragma unroll
    for (int nt = 0; nt < 2; ++nt) {
      const int n = n0b + ng * 32 + nt * 16 + l15;
      bf16x4 v;
      v[0] = (short)f2bf(acc[mt][nt][0]);
      v[1] = (short)f2bf(acc[mt][nt][1]);
      v[2] = (short)f2bf(acc[mt][nt][2]);
      v[3] = (short)f2bf(acc[mt][nt][3]);
      *(bf16x4*)&pb[(size_t)n * MSTRIDE + m0] = v;
    }
  }
}

// ------- Shared phase-1 helper: 16-col colbuf slice for col-group g --------
// Block of 256 threads: wave w handles cols g*16+4w .. +3; lane covers m=4*lane.
__device__ __forceinline__ void colbuf_slice(
    const unsigned short* __restrict__ part, const float* __restrict__ b3,
    const float* __restrict__ w4, const float* __restrict__ b4,
    int g, int t, float* scol /* LDS [16] */, float* s_cs, float* s_c4)
{
  const int lane = t & 63;
  const int w    = t >> 6;
  const int m    = lane * 4;

  float4 b3v = make_float4(0.f, 0.f, 0.f, 0.f);
  float4 w4v = make_float4(0.f, 0.f, 0.f, 0.f);
  if (m < C2) {
    b3v = *(const float4*)(b3 + m);
    w4v = *(const float4*)(w4 + m);
  }

#pragma unroll
  for (int q = 0; q < 4; ++q) {
    const int n = g * 16 + w * 4 + q;
    const unsigned short* p = part + (size_t)n * MSTRIDE + m;
    float4 s = make_float4(0.f, 0.f, 0.f, 0.f);
#pragma unroll
    for (int kcc = 0; kcc < KSPLIT; ++kcc) {
      bf16x4 v = *(const bf16x4*)(p + (size_t)kcc * PART_KC);
      s.x += bf2f((unsigned short)v[0]); s.y += bf2f((unsigned short)v[1]);
      s.z += bf2f((unsigned short)v[2]); s.w += bf2f((unsigned short)v[3]);
    }
    const float ex = fmaxf(s.x + b3v.x, 0.f), ey = fmaxf(s.y + b3v.y, 0.f);
    const float ez = fmaxf(s.z + b3v.z, 0.f), ew = fmaxf(s.w + b3v.w, 0.f);
    float cs = ex + ey + ez + ew;
    float c4 = ex * w4v.x + ey * w4v.y + ez * w4v.z + ew * w4v.w;
#pragma unroll
    for (int off = 32; off; off >>= 1) {
      cs += __shfl_xor(cs, off);
      c4 += __shfl_xor(c4, off);
    }
    if (lane == 0) { s_cs[w * 4 + q] = cs; s_c4[w * 4 + q] = c4; }
  }
  __syncthreads();
  if (t < 16) {
    const float mask = 1.f / (1.f + expf(-(s_c4[t] + b4[0])));
    scol[t] = s_cs[t] * (1.f + mask) * (1.f / (float)L_DIM);
  }
  __syncthreads();
}

// ------- Stage 2 (2-kernel path): colbuf slice + broadcast fused -----------
// 256 blocks: g = bid>>2 (col-group), h = bid&3 (row quarter of 2500 rows).
// 4 blocks recompute each 16-col slice (reads are L3-hot), then each writes
// its 64B column chunk to 2500 rows. No inter-block dependencies.
__global__ __launch_bounds__(256) void k_colcast(
    const unsigned short* __restrict__ part, const float* __restrict__ b3,
    const float* __restrict__ w4, const float* __restrict__ b4,
    float* __restrict__ out)
{
  __shared__ float scol[16], s_cs[16], s_c4[16];
  const int t = threadIdx.x;
  const int g = blockIdx.x >> 2;
  const int h = blockIdx.x & 3;

  colbuf_slice(part, b3, w4, b4, g, t, scol, s_cs, s_c4);

  const float v   = scol[t & 15];
  const int cofs  = g * 16 + (t & 15);
  const size_t r0 = (size_t)h * 2500;
  for (int r = t >> 4; r < 2500; r += 16)
    out[(r0 + r) * L_DIM + cofs] = v;
}

// ------- Stage 2a/2b (3-kernel fallback, partials in d_out) ----------------
__global__ __launch_bounds__(256) void k_colbuf(
    const unsigned short* __restrict__ part, const float* __restrict__ b3,
    const float* __restrict__ w4, const float* __restrict__ b4,
    float* __restrict__ colbuf)
{
  __shared__ float scol[16], s_cs[16], s_c4[16];
  const int t = threadIdx.x;
  const int g = blockIdx.x;
  colbuf_slice(part, b3, w4, b4, g, t, scol, s_cs, s_c4);
  if (t < 16) colbuf[g * 16 + t] = scol[t];
}

__global__ __launch_bounds__(256) void k_broadcast(
    const float* __restrict__ colbuf, float4* __restrict__ out)
{
  const size_t idx = (size_t)blockIdx.x * 256 + threadIdx.x;  // float4 index
  const int nq = (int)(idx & 255);
  const float4 v = *(const float4*)(colbuf + nq * 4);
  out[idx] = v;
}

extern "C" void kernel_launch(void* const* d_in, const int* in_sizes, int n_in,
                              void* d_out, int out_size, void* d_ws, size_t ws_size,
                              hipStream_t stream) {
  // inputs: x, edge_index, edge_attr, conv3_w, conv3_b, conv4_w, conv4_b
  const float* edge_attr = (const float*)d_in[2];   // [8192][1024]
  const float* w3        = (const float*)d_in[3];   // [240][8192]
  const float* b3        = (const float*)d_in[4];   // [240]
  const float* w4        = (const float*)d_in[5];   // [240]
  const float* b4        = (const float*)d_in[6];   // [1]

  float* out = (float*)d_out;

  if (ws_size >= PART_BYTES) {
    // 2-kernel path: partials in d_ws (no read/write race with output)
    unsigned short* part = (unsigned short*)d_ws;   // [16][1024][256] bf16
    k_gemm    <<<dim3(512), 256, 0, stream>>>(w3, edge_attr, part);
    k_colcast <<<dim3(256), 256, 0, stream>>>(part, b3, w4, b4, out);
  } else {
    // 3-kernel fallback: partials in d_out (overwritten by broadcast)
    unsigned short* part = (unsigned short*)d_out;
    float* colbuf = (float*)d_ws;                   // [1024] f32
    k_gemm      <<<dim3(512),   256, 0, stream>>>(w3, edge_attr, part);
    k_colbuf    <<<dim3(64),    256, 0, stream>>>(part, b3, w4, b4, colbuf);
    k_broadcast <<<dim3(10000), 256, 0, stream>>>(colbuf, (float4*)out);
  }
}

// Round 7
// 47.022 us; speedup vs baseline: 7.2186x; 1.0428x over previous
//
#include <hip/hip_runtime.h>
#include <hip/hip_bf16.h>

#define K_DIM 8192
#define L_DIM 1024
#define C2 240
#define MSTRIDE 256                 // padded m stride in partials
#define BM 128
#define BN 64
#define BK 64
#define KSPLIT 16
#define KCHUNK 512                  // K_DIM / KSPLIT
#define NSTEP 8                     // KCHUNK / BK
#define PART_KC (L_DIM * MSTRIDE)   // 262144 bf16 elems per k-chunk
#define PART_BYTES ((size_t)KSPLIT * PART_KC * 2)  // 8,388,608
#define TOT_F4 (10000 * 256)

typedef __attribute__((ext_vector_type(4))) float f32x4;
typedef __attribute__((ext_vector_type(8))) short bf16x8;
typedef __attribute__((ext_vector_type(4))) short bf16x4;

__device__ __forceinline__ unsigned short f2bf(float f) {
  return __builtin_bit_cast(unsigned short, __float2bfloat16(f));
}
__device__ __forceinline__ float bf2f(unsigned short h) {
  unsigned u = ((unsigned)h) << 16;
  return __builtin_bit_cast(float, u);
}

// ---------------- Stage 1: bf16 MFMA K-split GEMM --------------------------
// part[kc][n][m(pad 256)] = (W[240][8192] @ A[8192][1024]) k-chunk partials.
// 512 blocks x 256 thr (4 waves, 2m x 2n of 64x32), 3 blocks/CU (LDS 144KB).
// XCD-chunked remap: each XCD owns 2 consecutive k-chunks -> W/A L2-local.
__global__ __launch_bounds__(256, 3) void k_gemm(
    const float* __restrict__ Wm, const float* __restrict__ Am,
    unsigned short* __restrict__ part)
{
  __shared__ __align__(16) unsigned short sW[2 * BM * BK];  // 32 KB dbuf
  __shared__ __align__(16) unsigned short sA[2 * BN * BK];  // 16 KB dbuf

  const int t    = threadIdx.x;
  const int lane = t & 63;
  const int bid  = blockIdx.x;

  const int wk    = (bid & 7) * 64 + (bid >> 3);   // bijective (512%8==0)
  const int nt16  = wk & 15;
  const int mtile = (wk >> 4) & 1;
  const int kc    = wk >> 5;

  const int wid = t >> 6;
  const int mg  = wid & 1;        // 64-row group
  const int ng  = wid >> 1;       // 32-col group
  const int l15 = lane & 15;
  const int lk8 = (lane >> 4) * 8;

  const int n0b = nt16 * BN;
  const int m0b = mtile * BM;
  const int k0  = kc * KCHUNK;

  // staging: W thread -> (row t>>1, k-half (t&1)*32)
  // A: sak spans {0,4,8,12} within each quarter-wave so the XOR swizzle
  // spreads writes across slots (~2-4 way residual, near-free).
  const int swm = t >> 1;
  const int swk = (t & 1) * 32;
  const int san = ((t >> 2) & 15) * 4;
  const int sak = (t & 3) * 4 + (t >> 6) * 16;

  const float* wp = Wm + (size_t)(m0b + swm) * K_DIM + k0 + swk;
  const float* ap = Am + (size_t)(k0 + sak) * L_DIM + n0b + san;
  const bool wok = (m0b + swm) < C2;

  f32x4 wreg[8], areg[4];
  f32x4 acc[4][2];
#pragma unroll
  for (int i = 0; i < 4; ++i)
#pragma unroll
    for (int j = 0; j < 2; ++j) acc[i][j] = (f32x4){0.f, 0.f, 0.f, 0.f};

  // prefetch step 0
#pragma unroll
  for (int j = 0; j < 8; ++j)
    wreg[j] = wok ? *(const f32x4*)(wp + 4 * j) : (f32x4){0.f, 0.f, 0.f, 0.f};
#pragma unroll
  for (int r = 0; r < 4; ++r)
    areg[r] = *(const f32x4*)(ap + (size_t)r * L_DIM);

  for (int s = 0; s < NSTEP; ++s) {
    unsigned short* swb = sW + (s & 1) * (BM * BK);
    unsigned short* sab = sA + (s & 1) * (BN * BK);

    // convert + swizzled LDS write into buffer s&1
#pragma unroll
    for (int j = 0; j < 4; ++j) {
      f32x4 a = wreg[2 * j], b = wreg[2 * j + 1];
      bf16x8 v;
      v[0] = (short)f2bf(a[0]); v[1] = (short)f2bf(a[1]);
      v[2] = (short)f2bf(a[2]); v[3] = (short)f2bf(a[3]);
      v[4] = (short)f2bf(b[0]); v[5] = (short)f2bf(b[1]);
      v[6] = (short)f2bf(b[2]); v[7] = (short)f2bf(b[3]);
      *(bf16x8*)&swb[swm * BK + ((swk + 8 * j) ^ ((swm & 7) << 3))] = v;
    }
#pragma unroll
    for (int j = 0; j < 4; ++j) {
      int n = san + j;
      bf16x4 v;
      v[0] = (short)f2bf(areg[0][j]); v[1] = (short)f2bf(areg[1][j]);
      v[2] = (short)f2bf(areg[2][j]); v[3] = (short)f2bf(areg[3][j]);
      *(bf16x4*)&sab[n * BK + (sak ^ ((n & 7) << 3))] = v;
    }
    __syncthreads();
    // NOTE: barrier drain here is benign — no global loads outstanding at
    // this point (prev step's loads were consumed by the ds_writes above).

    // issue next step's global loads (overlap with MFMA below)
    if (s + 1 < NSTEP) {
      const float* wp2 = wp + (s + 1) * BK;
      const float* ap2 = ap + (size_t)(s + 1) * BK * L_DIM;
#pragma unroll
      for (int j = 0; j < 8; ++j)
        wreg[j] = wok ? *(const f32x4*)(wp2 + 4 * j) : (f32x4){0.f, 0.f, 0.f, 0.f};
#pragma unroll
      for (int r = 0; r < 4; ++r)
        areg[r] = *(const f32x4*)(ap2 + (size_t)r * L_DIM);
    }

    // compute from LDS buffer s&1
#pragma unroll
    for (int kk = 0; kk < BK; kk += 32) {
      bf16x8 wf[4], af[2];
#pragma unroll
      for (int mt = 0; mt < 4; ++mt) {
        int m = mg * 64 + mt * 16 + l15;
        wf[mt] = *(const bf16x8*)&swb[m * BK + ((kk + lk8) ^ ((m & 7) << 3))];
      }
#pragma unroll
      for (int nt = 0; nt < 2; ++nt) {
        int n = ng * 32 + nt * 16 + l15;
        af[nt] = *(const bf16x8*)&sab[n * BK + ((kk + lk8) ^ ((n & 7) << 3))];
      }
#pragma unroll
      for (int mt = 0; mt < 4; ++mt)
#pragma unroll
        for (int nt = 0; nt < 2; ++nt)
          acc[mt][nt] = __builtin_amdgcn_mfma_f32_16x16x32_bf16(
              wf[mt], af[nt], acc[mt][nt], 0, 0, 0);
    }
    // single barrier per step is safe: next write targets the other buffer
  }

  // store transposed bf16 partials: part[kc][n][m], 8B per lane
  // (m >= 240 rows are zeros via wok zero-fill -> safe to read downstream)
  unsigned short* pb = part + (size_t)kc * PART_KC;
#pragma unroll
  for (int mt = 0; mt < 4; ++mt) {
    const int m0 = m0b + mg * 64 + mt * 16 + (lane >> 4) * 4;
#pragma unroll
    for (int nt = 0; nt < 2; ++nt) {
      const int n = n0b + ng * 32 + nt * 16 + l15;
      bf16x4 v;
      v[0] = (short)f2bf(acc[mt][nt][0]);
      v[1] = (short)f2bf(acc[mt][nt][1]);
      v[2] = (short)f2bf(acc[mt][nt][2]);
      v[3] = (short)f2bf(acc[mt][nt][3]);
      *(bf16x4*)&pb[(size_t)n * MSTRIDE + m0] = v;
    }
  }
}

// ---------------- Stage 2: kc-reduce + bias + ReLU + m-reductions ----------
// One block per column n: thread t = m (coalesced 2B reads across t).
__global__ __launch_bounds__(256) void k_colbuf(
    const unsigned short* __restrict__ part, const float* __restrict__ b3,
    const float* __restrict__ w4, const float* __restrict__ b4,
    float* __restrict__ colbuf)
{
  __shared__ float red[2][4];
  const int n = blockIdx.x;
  const int t = threadIdx.x;
  const unsigned short* p = part + (size_t)n * MSTRIDE + t;
  float s = 0.f;
#pragma unroll
  for (int kcc = 0; kcc < KSPLIT; ++kcc)
    s += bf2f(p[(size_t)kcc * PART_KC]);
  float e = 0.f, c4 = 0.f;
  if (t < C2) {
    e  = fmaxf(s + b3[t], 0.f);
    c4 = w4[t] * e;
  }
#pragma unroll
  for (int off = 32; off; off >>= 1) {
    e  += __shfl_xor(e, off);
    c4 += __shfl_xor(c4, off);
  }
  const int wv = t >> 6;
  if ((t & 63) == 0) { red[0][wv] = e; red[1][wv] = c4; }
  __syncthreads();
  if (t == 0) {
    const float cs  = red[0][0] + red[0][1] + red[0][2] + red[0][3];
    const float tc4 = red[1][0] + red[1][1] + red[1][2] + red[1][3] + b4[0];
    const float mask = 1.f / (1.f + expf(-tc4));
    colbuf[n] = cs * (1.f + mask) * (1.f / (float)L_DIM);
  }
}

// ---------------- Stage 3: broadcast to all nodes (fully coalesced) --------
__global__ __launch_bounds__(256) void k_broadcast(
    const float* __restrict__ colbuf, float4* __restrict__ out)
{
  const size_t idx = (size_t)blockIdx.x * 256 + threadIdx.x;  // float4 index
  const int nq = (int)(idx & 255);
  const float4 v = *(const float4*)(colbuf + nq * 4);
  out[idx] = v;
}

extern "C" void kernel_launch(void* const* d_in, const int* in_sizes, int n_in,
                              void* d_out, int out_size, void* d_ws, size_t ws_size,
                              hipStream_t stream) {
  // inputs: x, edge_index, edge_attr, conv3_w, conv3_b, conv4_w, conv4_b
  const float* edge_attr = (const float*)d_in[2];   // [8192][1024]
  const float* w3        = (const float*)d_in[3];   // [240][8192]
  const float* b3        = (const float*)d_in[4];   // [240]
  const float* w4        = (const float*)d_in[5];   // [240]
  const float* b4        = (const float*)d_in[6];   // [1]

  float* out = (float*)d_out;

  // partials in d_ws (measured ws_size ~268MB >> 8.4MB); colbuf after them.
  // Fallback to d_out-scratch layout if ws is unexpectedly tiny.
  unsigned short* part;
  float* colbuf;
  if (ws_size >= PART_BYTES + 4096) {
    part   = (unsigned short*)d_ws;
    colbuf = (float*)((char*)d_ws + PART_BYTES);
  } else {
    part   = (unsigned short*)d_out;   // overwritten by broadcast afterwards
    colbuf = (float*)d_ws;
  }

  k_gemm      <<<dim3(512),   256, 0, stream>>>(w3, edge_attr, part);
  k_colbuf    <<<dim3(1024),  256, 0, stream>>>(part, b3, w4, b4, colbuf);
  k_broadcast <<<dim3(10000), 256, 0, stream>>>(colbuf, (float4*)out);
}

// Round 8
// 31.299 us; speedup vs baseline: 10.8451x; 1.5024x over previous
//
#include <hip/hip_runtime.h>
#include <hip/hip_bf16.h>

#define K_DIM 8192
#define L_DIM 1024
#define C2 240
#define MSTRIDE 256                 // padded m stride in partials
#define BM 128
#define BN 128
#define BK 64
#define KSPLIT 16
#define KCHUNK 512                  // K_DIM / KSPLIT
#define NSTEP 8                     // KCHUNK / BK
#define PART_KC (L_DIM * MSTRIDE)   // 262144 bf16 elems per k-chunk
#define PART_BYTES ((size_t)KSPLIT * PART_KC * 2)  // 8,388,608
#define TOT_F4 (10000 * 256)

typedef __attribute__((ext_vector_type(4))) float f32x4;
typedef __attribute__((ext_vector_type(2))) float f32x2;
typedef __attribute__((ext_vector_type(8))) short bf16x8;
typedef __attribute__((ext_vector_type(4))) short bf16x4;

__device__ __forceinline__ unsigned short f2bf(float f) {
  return __builtin_bit_cast(unsigned short, __float2bfloat16(f));
}
__device__ __forceinline__ float bf2f(unsigned short h) {
  unsigned u = ((unsigned)h) << 16;
  return __builtin_bit_cast(float, u);
}

// ---------------- Stage 1: bf16 MFMA K-split GEMM --------------------------
// part[kc][n][m(pad 256)] = (W[240][8192] @ A[8192][1024]) k-chunk partials.
// 256 blocks x 512 thr (8 waves: 2m x 4n groups of 64x32), 1 block/CU.
// BN=128 (256KB/block for 8.4M MACs — R3's traffic shape, vs R7's 384KB).
// Depth-2 register prefetch + double-buffered LDS, single barrier/step.
__global__ __launch_bounds__(512, 2) void k_gemm(
    const float* __restrict__ Wm, const float* __restrict__ Am,
    unsigned short* __restrict__ part)
{
  __shared__ __align__(16) unsigned short sW[2 * BM * BK];  // 32 KB dbuf
  __shared__ __align__(16) unsigned short sA[2 * BN * BK];  // 32 KB dbuf

  const int t    = threadIdx.x;
  const int lane = t & 63;
  const int bid  = blockIdx.x;

  // XCD-chunked remap (bijective, 256 % 8 == 0): XCD owns 2 kc x all tiles.
  const int wk    = (bid & 7) * 32 + (bid >> 3);
  const int nt8   = wk & 7;
  const int mtile = (wk >> 3) & 1;
  const int kc    = wk >> 4;            // 0..15

  const int wid = t >> 6;
  const int mg  = wid >> 2;       // 2 groups of 64 m
  const int ng  = wid & 3;        // 4 groups of 32 n
  const int l15 = lane & 15;
  const int lk8 = (lane >> 4) * 8;

  const int n0b = nt8 * BN;
  const int m0b = mtile * BM;
  const int k0  = kc * KCHUNK;

  // W staging: thread -> (row t>>2, 16 k at (t&3)*16); 4 f32x4 loads.
  const int swm = t >> 2;
  const int swk = (t & 3) * 16;
  // A staging: thread -> (2 cols at 2*(t&63), 8 k at wid*8); 8 f32x2 loads.
  // n&7 spans both parities across lanes -> XOR swizzle spreads banks.
  const int san = (t & 63) * 2;
  const int sak = (t >> 6) * 8;

  const float* wp = Wm + (size_t)(m0b + swm) * K_DIM + k0 + swk;
  const float* ap = Am + (size_t)(k0 + sak) * L_DIM + n0b + san;
  const bool wok = (m0b + swm) < C2;

  f32x4 wregs[2][4];
  f32x2 aregs[2][8];
  f32x4 acc[4][2];
#pragma unroll
  for (int i = 0; i < 4; ++i)
#pragma unroll
    for (int j = 0; j < 2; ++j) acc[i][j] = (f32x4){0.f, 0.f, 0.f, 0.f};

  // prologue: issue loads for steps 0 and 1 (depth-2)
#pragma unroll
  for (int p = 0; p < 2; ++p) {
#pragma unroll
    for (int j = 0; j < 4; ++j)
      wregs[p][j] = wok ? *(const f32x4*)(wp + p * BK + 4 * j)
                        : (f32x4){0.f, 0.f, 0.f, 0.f};
#pragma unroll
    for (int r = 0; r < 8; ++r)
      aregs[p][r] = *(const f32x2*)(ap + (size_t)(p * BK + r) * L_DIM);
  }

#pragma unroll
  for (int s = 0; s < NSTEP; ++s) {
    unsigned short* swb = sW + (s & 1) * (BM * BK);
    unsigned short* sab = sA + (s & 1) * (BN * BK);

    // ---- convert + swizzled LDS write from reg set s&1 ----
#pragma unroll
    for (int j = 0; j < 2; ++j) {       // two bf16x8 per thread (16 k)
      f32x4 a = wregs[s & 1][2 * j], b = wregs[s & 1][2 * j + 1];
      bf16x8 v;
      v[0] = (short)f2bf(a[0]); v[1] = (short)f2bf(a[1]);
      v[2] = (short)f2bf(a[2]); v[3] = (short)f2bf(a[3]);
      v[4] = (short)f2bf(b[0]); v[5] = (short)f2bf(b[1]);
      v[6] = (short)f2bf(b[2]); v[7] = (short)f2bf(b[3]);
      *(bf16x8*)&swb[swm * BK + ((swk + 8 * j) ^ ((swm & 7) << 3))] = v;
    }
#pragma unroll
    for (int j = 0; j < 2; ++j) {       // two cols, 8 k each
      const int n = san + j;
      bf16x8 v;
#pragma unroll
      for (int r = 0; r < 8; ++r)
        v[r] = (short)f2bf(j ? aregs[s & 1][r][1] : aregs[s & 1][r][0]);
      *(bf16x8*)&sab[n * BK + (sak ^ ((n & 7) << 3))] = v;
    }
    __syncthreads();

    // ---- issue loads for step s+2 into reg set s&1 (depth-2 cover) ----
    if (s + 2 < NSTEP) {
      const float* wp2 = wp + (s + 2) * BK;
      const float* ap2 = ap + (size_t)(s + 2) * BK * L_DIM;
#pragma unroll
      for (int j = 0; j < 4; ++j)
        wregs[s & 1][j] = wok ? *(const f32x4*)(wp2 + 4 * j)
                              : (f32x4){0.f, 0.f, 0.f, 0.f};
#pragma unroll
      for (int r = 0; r < 8; ++r)
        aregs[s & 1][r] = *(const f32x2*)(ap2 + (size_t)r * L_DIM);
    }

    // ---- compute from LDS buffer s&1 ----
#pragma unroll
    for (int kk = 0; kk < BK; kk += 32) {
      bf16x8 wf[4], af[2];
#pragma unroll
      for (int mt = 0; mt < 4; ++mt) {
        int m = mg * 64 + mt * 16 + l15;
        wf[mt] = *(const bf16x8*)&swb[m * BK + ((kk + lk8) ^ ((m & 7) << 3))];
      }
#pragma unroll
      for (int nt = 0; nt < 2; ++nt) {
        int n = ng * 32 + nt * 16 + l15;
        af[nt] = *(const bf16x8*)&sab[n * BK + ((kk + lk8) ^ ((n & 7) << 3))];
      }
#pragma unroll
      for (int mt = 0; mt < 4; ++mt)
#pragma unroll
        for (int nt = 0; nt < 2; ++nt)
          acc[mt][nt] = __builtin_amdgcn_mfma_f32_16x16x32_bf16(
              wf[mt], af[nt], acc[mt][nt], 0, 0, 0);
    }
    // single barrier/step: next iteration writes the other LDS buffer
  }

  // store transposed bf16 partials: part[kc][n][m]; each block fully
  // dirties its 128B L2 lines (m-range contiguous) -> full-line evictions.
  unsigned short* pb = part + (size_t)kc * PART_KC;
#pragma unroll
  for (int mt = 0; mt < 4; ++mt) {
    const int m0 = m0b + mg * 64 + mt * 16 + (lane >> 4) * 4;
#pragma unroll
    for (int nt = 0; nt < 2; ++nt) {
      const int n = n0b + ng * 32 + nt * 16 + l15;
      bf16x4 v;
      v[0] = (short)f2bf(acc[mt][nt][0]);
      v[1] = (short)f2bf(acc[mt][nt][1]);
      v[2] = (short)f2bf(acc[mt][nt][2]);
      v[3] = (short)f2bf(acc[mt][nt][3]);
      *(bf16x4*)&pb[(size_t)n * MSTRIDE + m0] = v;
    }
  }
}

// ---------------- Stage 2: kc-reduce + bias + ReLU + m-reductions ----------
// One block per column n: thread t = m (coalesced 2B reads across t).
__global__ __launch_bounds__(256) void k_colbuf(
    const unsigned short* __restrict__ part, const float* __restrict__ b3,
    const float* __restrict__ w4, const float* __restrict__ b4,
    float* __restrict__ colbuf)
{
  __shared__ float red[2][4];
  const int n = blockIdx.x;
  const int t = threadIdx.x;
  const unsigned short* p = part + (size_t)n * MSTRIDE + t;
  float s = 0.f;
#pragma unroll
  for (int kcc = 0; kcc < KSPLIT; ++kcc)
    s += bf2f(p[(size_t)kcc * PART_KC]);
  float e = 0.f, c4 = 0.f;
  if (t < C2) {
    e  = fmaxf(s + b3[t], 0.f);
    c4 = w4[t] * e;
  }
#pragma unroll
  for (int off = 32; off; off >>= 1) {
    e  += __shfl_xor(e, off);
    c4 += __shfl_xor(c4, off);
  }
  const int wv = t >> 6;
  if ((t & 63) == 0) { red[0][wv] = e; red[1][wv] = c4; }
  __syncthreads();
  if (t == 0) {
    const float cs  = red[0][0] + red[0][1] + red[0][2] + red[0][3];
    const float tc4 = red[1][0] + red[1][1] + red[1][2] + red[1][3] + b4[0];
    const float mask = 1.f / (1.f + expf(-tc4));
    colbuf[n] = cs * (1.f + mask) * (1.f / (float)L_DIM);
  }
}

// ---------------- Stage 3: broadcast to all nodes (fully coalesced) --------
__global__ __launch_bounds__(256) void k_broadcast(
    const float* __restrict__ colbuf, float4* __restrict__ out)
{
  const size_t idx = (size_t)blockIdx.x * 256 + threadIdx.x;  // float4 index
  const int nq = (int)(idx & 255);
  const float4 v = *(const float4*)(colbuf + nq * 4);
  out[idx] = v;
}

extern "C" void kernel_launch(void* const* d_in, const int* in_sizes, int n_in,
                              void* d_out, int out_size, void* d_ws, size_t ws_size,
                              hipStream_t stream) {
  // inputs: x, edge_index, edge_attr, conv3_w, conv3_b, conv4_w, conv4_b
  const float* edge_attr = (const float*)d_in[2];   // [8192][1024]
  const float* w3        = (const float*)d_in[3];   // [240][8192]
  const float* b3        = (const float*)d_in[4];   // [240]
  const float* w4        = (const float*)d_in[5];   // [240]
  const float* b4        = (const float*)d_in[6];   // [1]

  float* out = (float*)d_out;

  // partials in d_ws (measured ws_size ~268MB >> 8.4MB); colbuf after them.
  unsigned short* part;
  float* colbuf;
  if (ws_size >= PART_BYTES + 4096) {
    part   = (unsigned short*)d_ws;
    colbuf = (float*)((char*)d_ws + PART_BYTES);
  } else {
    part   = (unsigned short*)d_out;   // overwritten by broadcast afterwards
    colbuf = (float*)d_ws;
  }

  k_gemm      <<<dim3(256),   512, 0, stream>>>(w3, edge_attr, part);
  k_colbuf    <<<dim3(1024),  256, 0, stream>>>(part, b3, w4, b4, colbuf);
  k_broadcast <<<dim3(10000), 256, 0, stream>>>(colbuf, (float4*)out);
}